// Round 2
// baseline (146.814 us; speedup 1.0000x reference)
//
#include <hip/hip_runtime.h>

#define NB 2
#define NC 16
#define NH 128
#define NW 256
#define NCW 32
#define NWE 287            // NW + NCW - 1 (left image zero-extended right)
#define HW (NH*NW)
#define PATCH_INV (1.0f/784.0f)
#define EPS_N 1e-9f

// One block per (d-quarter, y, b). 256 threads = one per x.
// cost[b,y,x,d] = (S_LR - SL*SR/784) * invL * invR
//   S_LR = 7x7 box filter of prod_d[y,x] = sum_c L[c,y,x+d]*R[c,y,x]
//   SL,S2L over left extended width (columns >=256 are zero)
__global__ __launch_bounds__(256) void ncc_cost_kernel(
    const float* __restrict__ L,
    const float* __restrict__ R,
    float* __restrict__ out)
{
    const int x  = threadIdx.x;
    const int dq = blockIdx.x;     // 0..3
    const int y  = blockIdx.y;     // 0..127
    const int b  = blockIdx.z;     // 0..1
    const int d0 = dq * 8;

    __shared__ float sSL[NWE];
    __shared__ float sInvL[NWE];
    __shared__ float buf[2048];    // phase1: cs arrays; phase3: vp[8][256]

    float* csL  = buf;             // [320] (287 used)
    float* cs2L = buf + 320;
    float* csR  = buf + 640;       // [256]
    float* cs2R = buf + 896;

    // ---- phase 1: channel + vertical (7-row) sums per column ----
    float aL = 0.f, a2L = 0.f, aR = 0.f, a2R = 0.f;
    const size_t base = (size_t)b * NC * HW;
    for (int dy = -3; dy <= 3; ++dy) {
        int yy = y + dy;
        if ((unsigned)yy < NH) {
            const float* lp = L + base + (size_t)yy * NW + x;
            const float* rp = R + base + (size_t)yy * NW + x;
            #pragma unroll
            for (int c = 0; c < NC; ++c) {
                float lv = lp[c * HW];
                float rv = rp[c * HW];
                aL += lv; a2L += lv * lv;
                aR += rv; a2R += rv * rv;
            }
        }
    }
    csL[x] = aL; cs2L[x] = a2L;
    csR[x] = aR; cs2R[x] = a2R;
    if (x < NWE - NW) { csL[NW + x] = 0.f; cs2L[NW + x] = 0.f; }  // ext cols zero
    __syncthreads();

    // ---- phase 2: horizontal 7-tap -> per-pixel patch stats ----
    #pragma unroll
    for (int rep = 0; rep < 2; ++rep) {
        int xe = x + rep * NW;             // covers 0..286
        if (xe < NWE) {
            float S = 0.f, S2 = 0.f;
            #pragma unroll
            for (int dx = -3; dx <= 3; ++dx) {
                int xx = xe + dx;
                if ((unsigned)xx < NWE) { S += csL[xx]; S2 += cs2L[xx]; }
            }
            sSL[xe]   = S;
            sInvL[xe] = rsqrtf(S2 - S * S * PATCH_INV + EPS_N);
        }
    }
    float SRx = 0.f, S2R = 0.f;
    #pragma unroll
    for (int dx = -3; dx <= 3; ++dx) {
        int xx = x + dx;
        if ((unsigned)xx < NW) { SRx += csR[xx]; S2R += cs2R[xx]; }
    }
    const float invRx = rsqrtf(S2R - SRx * SRx * PATCH_INV + EPS_N);
    __syncthreads();   // cs arrays dead; buf reused for vp below

    // ---- phase 3: vertical (7-row, 16-ch) product sums for 8 disparities ----
    float vp[8] = {0,0,0,0,0,0,0,0};
    for (int dy = -3; dy <= 3; ++dy) {
        int yy = y + dy;
        if ((unsigned)yy < NH) {
            const float* lrow = L + base + (size_t)yy * NW;
            const float* rrow = R + base + (size_t)yy * NW;
            for (int c = 0; c < NC; ++c) {
                float rv = rrow[c * HW + x];
                const float* lr = lrow + c * HW;
                #pragma unroll
                for (int j = 0; j < 8; ++j) {
                    int xl = x + d0 + j;
                    float lv = (xl < NW) ? lr[xl] : 0.f;   // left ext region is zero
                    vp[j] += lv * rv;
                }
            }
        }
    }
    #pragma unroll
    for (int j = 0; j < 8; ++j) buf[j * NW + x] = vp[j];
    __syncthreads();

    // ---- phase 4: horizontal 7-tap + normalize + store ----
    float res[8];
    #pragma unroll
    for (int j = 0; j < 8; ++j) {
        float s = 0.f;
        #pragma unroll
        for (int dx = -3; dx <= 3; ++dx) {
            int xx = x + dx;
            if ((unsigned)xx < NW) s += buf[j * NW + xx];
        }
        int xl = x + d0 + j;
        res[j] = (s - sSL[xl] * SRx * PATCH_INV) * sInvL[xl] * invRx;
    }
    float4* op = (float4*)(out + ((size_t)(b * NH + y) * NW + x) * NCW + d0);
    op[0] = make_float4(res[0], res[1], res[2], res[3]);
    op[1] = make_float4(res[4], res[5], res[6], res[7]);
}

extern "C" void kernel_launch(void* const* d_in, const int* in_sizes, int n_in,
                              void* d_out, int out_size, void* d_ws, size_t ws_size,
                              hipStream_t stream) {
    const float* L = (const float*)d_in[0];
    const float* R = (const float*)d_in[1];
    float* out = (float*)d_out;
    dim3 grid(4, NH, NB);
    ncc_cost_kernel<<<grid, dim3(256), 0, stream>>>(L, R, out);
}

// Round 4
// 84.793 us; speedup vs baseline: 1.7314x; 1.7314x over previous
//
#include <hip/hip_runtime.h>

#define NB 2
#define NC 16
#define NH 128
#define NW 256
#define NCW 32
#define HW (NH*NW)
#define PATCH_INV (1.0f/784.0f)
#define EPS_N 1e-9f
#define HB_W 272   // hbuf row: [0..3]=0, [4..259]=prod cols 0..255, [260..271]=0

// One block per (b,y); 256 threads = 64 x-groups (4 cols) x 4 d-groups (8 disps).
// cost[b,y,x,d] = (S_LR - SL*SR/784) * invL * invR, separable 7x7 box sums.
__global__ __launch_bounds__(256) void ncc_kernel(
    const float* __restrict__ L, const float* __restrict__ R, float* __restrict__ out)
{
    __shared__ float csL[NW], cs2L[NW], csR[NW], cs2R[NW];
    __shared__ float sSL[288], sInvL[288], sSR[NW], sInvR[NW];
    __shared__ float hbuf[NCW][HB_W];

    // XCD-aware bijective swizzle (256 = 8 XCDs x 32 consecutive rows)
    const int bid = blockIdx.x;
    const int lin = (bid & 7) * 32 + (bid >> 3);
    const int b = lin >> 7;
    const int y = lin & 127;

    const int t  = threadIdx.x;
    const int dq = t >> 6;
    const int xg = t & 63;
    const int x0 = xg << 2;
    const int d0 = dq << 3;
    const int s  = x0 + d0;          // left window base (<=276)

    const size_t base = (size_t)b * NC * HW;

    // ---- phase A: column stats (round-2 verbatim; thread t = column t) ----
    {
        float aL = 0.f, a2L = 0.f, aR = 0.f, a2R = 0.f;
        #pragma unroll
        for (int dy = -3; dy <= 3; ++dy) {
            int yy = y + dy;
            if ((unsigned)yy < NH) {
                const float* lp = L + base + (size_t)yy * NW + t;
                const float* rp = R + base + (size_t)yy * NW + t;
                #pragma unroll
                for (int c = 0; c < NC; ++c) {
                    float lv = lp[c * HW];
                    float rv = rp[c * HW];
                    aL += lv; a2L += lv * lv;
                    aR += rv; a2R += rv * rv;
                }
            }
        }
        csL[t] = aL; cs2L[t] = a2L; csR[t] = aR; cs2R[t] = a2R;
    }
    __syncthreads();

    // ---- phase B: horizontal 7-tap -> per-pixel patch stats (round-2 verbatim) ----
    #pragma unroll
    for (int rep = 0; rep < 2; ++rep) {
        int xe = t + rep * 256;
        if (xe < 288) {
            float S = 0.f, S2 = 0.f;
            #pragma unroll
            for (int dx = -3; dx <= 3; ++dx) {
                int xx = xe + dx;
                if ((unsigned)xx < NW) { S += csL[xx]; S2 += cs2L[xx]; }
            }
            sSL[xe]   = S;
            sInvL[xe] = rsqrtf(S2 - S * S * PATCH_INV + EPS_N);
        }
    }
    {
        float S = 0.f, S2 = 0.f;
        #pragma unroll
        for (int dx = -3; dx <= 3; ++dx) {
            int xx = t + dx;
            if ((unsigned)xx < NW) { S += csR[xx]; S2 += cs2R[xx]; }
        }
        sSR[t]   = S;
        sInvR[t] = rsqrtf(S2 - S * S * PATCH_INV + EPS_N);
    }
    __syncthreads();

    // ---- phase C: per-column channel+row product sums, 4 cols x 8 disps ----
    float vp[4][8];
    #pragma unroll
    for (int i = 0; i < 4; ++i)
        #pragma unroll
        for (int j = 0; j < 8; ++j) vp[i][j] = 0.f;

    #pragma unroll
    for (int dy = -3; dy <= 3; ++dy) {
        const int yy = y + dy;
        if ((unsigned)yy < NH) {
            const float* lrow = L + base + (size_t)yy * NW;
            const float* rrow = R + base + (size_t)yy * NW;
            #pragma unroll
            for (int c = 0; c < NC; ++c) {
                const float* lc = lrow + (size_t)c * HW;
                const float* rc = rrow + (size_t)c * HW;
                float4 rv4 = *(const float4*)(rc + x0);
                float rv[4] = {rv4.x, rv4.y, rv4.z, rv4.w};
                float lw[12];
                #pragma unroll
                for (int ch = 0; ch < 3; ++ch) {
                    int col  = s + ch * 4;                       // multiple of 4
                    int colc = col < (NW - 4) ? col : (NW - 4);  // always-valid addr
                    float4 lv = *(const float4*)(lc + colc);
                    bool ok = (col < NW);                        // ext region zero
                    lw[ch*4+0] = ok ? lv.x : 0.f;
                    lw[ch*4+1] = ok ? lv.y : 0.f;
                    lw[ch*4+2] = ok ? lv.z : 0.f;
                    lw[ch*4+3] = ok ? lv.w : 0.f;
                }
                #pragma unroll
                for (int xx = 0; xx < 4; ++xx)
                    #pragma unroll
                    for (int j = 0; j < 8; ++j)
                        vp[xx][j] += lw[xx + j] * rv[xx];
            }
        }
    }
    #pragma unroll
    for (int j = 0; j < 8; ++j)
        *(float4*)&hbuf[d0 + j][4 + x0] =
            make_float4(vp[0][j], vp[1][j], vp[2][j], vp[3][j]);
    if (t < 128) {   // zero halo pads: cols 0..3 and 260..271 of each d-row
        int r = t >> 2, q = t & 3;
        int col = (q == 0) ? 0 : (260 + 4 * (q - 1));
        *(float4*)&hbuf[r][col] = make_float4(0.f, 0.f, 0.f, 0.f);
    }
    __syncthreads();

    // ---- phase D: fresh ascending 7-tap + normalize + store ----
    float res[4][8];
    #pragma unroll
    for (int j = 0; j < 8; ++j) {
        float4 w0 = *(float4*)&hbuf[d0+j][x0];
        float4 w1 = *(float4*)&hbuf[d0+j][x0+4];
        float4 w2 = *(float4*)&hbuf[d0+j][x0+8];
        float w[12] = {w0.x,w0.y,w0.z,w0.w, w1.x,w1.y,w1.z,w1.w, w2.x,w2.y,w2.z,w2.w};
        #pragma unroll
        for (int xx = 0; xx < 4; ++xx) {
            float sum = 0.f;
            #pragma unroll
            for (int k = 1; k <= 7; ++k) sum += w[xx + k];
            float slv = sSL[s + xx + j];
            float ilv = sInvL[s + xx + j];
            float srv = sSR[x0 + xx];
            float irv = sInvR[x0 + xx];
            res[xx][j] = (sum - slv * srv * PATCH_INV) * ilv * irv;
        }
    }

    float* op = out + (((size_t)(b * NH + y) * NW) + x0) * NCW + d0;
    #pragma unroll
    for (int xx = 0; xx < 4; ++xx) {
        *(float4*)(op + (size_t)xx * NCW)     =
            make_float4(res[xx][0], res[xx][1], res[xx][2], res[xx][3]);
        *(float4*)(op + (size_t)xx * NCW + 4) =
            make_float4(res[xx][4], res[xx][5], res[xx][6], res[xx][7]);
    }
}

extern "C" void kernel_launch(void* const* d_in, const int* in_sizes, int n_in,
                              void* d_out, int out_size, void* d_ws, size_t ws_size,
                              hipStream_t stream) {
    const float* L = (const float*)d_in[0];
    const float* R = (const float*)d_in[1];
    float* out = (float*)d_out;
    ncc_kernel<<<dim3(NB * NH), dim3(256), 0, stream>>>(L, R, out);
}